// Round 5
// baseline (564.597 us; speedup 1.0000x reference)
//
#include <hip/hip_runtime.h>

#define D_IN 256
#define D_OUT 128
#define NEG_SLOPE 0.2
#define CAP 128   // per-row LDS coefficient cache in row_kernel

typedef __attribute__((ext_vector_type(8))) short s16x8;   // 8 bf16 (4 VGPRs)
typedef __attribute__((ext_vector_type(4))) float f32x4;   // MFMA C/D frag

__device__ __forceinline__ unsigned short f2bf(float f) {   // fp32 -> bf16 RNE
    unsigned u = __float_as_uint(f);
    u += 0x7FFFu + ((u >> 16) & 1u);
    return (unsigned short)(u >> 16);
}
__device__ __forceinline__ float bf2f(unsigned short h) {
    return __uint_as_float(((unsigned)h) << 16);
}

// ---------------------------------------------------------------------------
// Dispatch 1: block 0          : wa[k]     = sum_n W[k][n]*a_src[n]  (fp64)
//                                wa[256+k] = sum_n W[k][n]*a_dst[n]
//             blocks [1,129)   : W -> wt_h/wt_l [n][k] bf16 split
//             blocks [129, ...): counts histogram of src
// ---------------------------------------------------------------------------
__global__ __launch_bounds__(256) void prep_count(
    const float* __restrict__ W, const float* __restrict__ a,
    double* __restrict__ wa,
    unsigned short* __restrict__ wth, unsigned short* __restrict__ wtl,
    const int* __restrict__ src, int* __restrict__ counts, int E) {
    if (blockIdx.x == 0) {
        int k = threadIdx.x;            // 0..255
        double s = 0.0, d = 0.0;
        for (int n = 0; n < D_OUT; ++n) {
            double w = (double)W[k * D_OUT + n];
            s += w * (double)a[n];
            d += w * (double)a[D_OUT + n];
        }
        wa[k] = s;
        wa[D_IN + k] = d;
        return;
    }
    if (blockIdx.x <= 128) {
        int idx = (blockIdx.x - 1) * 256 + threadIdx.x;   // 0..32767
        int n = idx & 127;                                 // coalesced read
        int k = idx >> 7;
        float w = W[k * D_OUT + n];
        unsigned short h = f2bf(w);
        wth[(size_t)n * D_IN + k] = h;
        wtl[(size_t)n * D_IN + k] = f2bf(w - bf2f(h));
        return;
    }
    int bid  = blockIdx.x - 129;
    int base = (bid * 256 + (int)threadIdx.x) * 4;
    if (base + 4 <= E) {
        int4 s4 = *(const int4*)(src + base);
        atomicAdd(&counts[s4.x], 1); atomicAdd(&counts[s4.y], 1);
        atomicAdd(&counts[s4.z], 1); atomicAdd(&counts[s4.w], 1);
    } else {
        for (int i = base; i < E; ++i) atomicAdd(&counts[src[i]], 1);
    }
}

// ---------------------------------------------------------------------------
// Dispatch 2: block 0       : exclusive scan counts -> rowptr, cursor
//             blocks 1..782 : split-bf16 MFMA GEMM m = x@W (64 rows/block,
//                             16 rows/wave), fp32 m out, PLUS fused fp64
//                             s/d = x . wa accumulated in the K-loop (exact
//                             e-path, independent of GEMM precision).
// A-frag: A[m=lane&15][k=(lane>>4)*8+j]; B-frag: B[k=(lane>>4)*8+j][n=lane&15]
// C/D   : col = lane&15, row = (lane>>4)*4 + reg
// ---------------------------------------------------------------------------
__global__ __launch_bounds__(256, 3) void gemm_sd_scan(
    const float* __restrict__ x,
    const unsigned short* __restrict__ wth, const unsigned short* __restrict__ wtl,
    const double* __restrict__ wa,
    float* __restrict__ m,
    double* __restrict__ svec, double* __restrict__ dvec,
    const int* __restrict__ counts, int* __restrict__ rowptr,
    int* __restrict__ cursor, int M) {
    __shared__ int part[256];
    if (blockIdx.x == 0) {
        int t = threadIdx.x;
        int chunk = (M + 255) >> 8;
        int b = t * chunk, e = min(b + chunk, M);
        int s = 0;
        for (int i = b; i < e; ++i) s += counts[i];
        part[t] = s;
        __syncthreads();
        for (int off = 1; off < 256; off <<= 1) {
            int v = (t >= off) ? part[t - off] : 0;
            __syncthreads();
            part[t] += v;
            __syncthreads();
        }
        int running = (t == 0) ? 0 : part[t - 1];
        for (int i = b; i < e; ++i) {
            rowptr[i] = running; cursor[i] = running; running += counts[i];
        }
        if (t == 255) rowptr[M] = part[255];
        return;
    }

    const int blk  = blockIdx.x - 1;
    const int wave = threadIdx.x >> 6;
    const int lane = threadIdx.x & 63;
    const int c    = lane & 15;        // A row offset / B col offset / C col
    const int q    = lane >> 4;        // k quad
    const int r0   = blk * 64 + wave * 16;

    const int arow  = r0 + c;
    const int arowc = (arow < M) ? arow : (M - 1);   // clamp; stores guarded

    f32x4 acc[8];
#pragma unroll
    for (int t = 0; t < 8; ++t) acc[t] = (f32x4){0.f, 0.f, 0.f, 0.f};
    double ps = 0.0, pd = 0.0;

#pragma unroll
    for (int kt = 0; kt < 8; ++kt) {
        const int kb = kt * 32 + q * 8;
        const float* xp = x + (size_t)arowc * D_IN + kb;
        float4 a0 = *(const float4*)xp;
        float4 a1 = *(const float4*)(xp + 4);
        float av[8] = {a0.x, a0.y, a0.z, a0.w, a1.x, a1.y, a1.z, a1.w};
        // fused fp64 s/d partials (exact e-path): x . wa
#pragma unroll
        for (int j = 0; j < 8; ++j) {
            ps += (double)av[j] * wa[kb + j];
            pd += (double)av[j] * wa[D_IN + kb + j];
        }
        // bf16 split of x fragment
        s16x8 ah, al;
#pragma unroll
        for (int j = 0; j < 8; ++j) {
            unsigned short h = f2bf(av[j]);
            ah[j] = (short)h;
            al[j] = (short)f2bf(av[j] - bf2f(h));
        }
#pragma unroll
        for (int t = 0; t < 8; ++t) {
            size_t boff = ((size_t)(t * 16 + c)) * D_IN + kb;
            s16x8 bh = *(const s16x8*)(wth + boff);
            s16x8 bl = *(const s16x8*)(wtl + boff);
            acc[t] = __builtin_amdgcn_mfma_f32_16x16x32_bf16(al, bh, acc[t], 0, 0, 0);
            acc[t] = __builtin_amdgcn_mfma_f32_16x16x32_bf16(ah, bl, acc[t], 0, 0, 0);
            acc[t] = __builtin_amdgcn_mfma_f32_16x16x32_bf16(ah, bh, acc[t], 0, 0, 0);
        }
    }

    // s/d: reduce partials across the 4 k-quads (lanes sharing c)
    ps += __shfl_xor(ps, 16); ps += __shfl_xor(ps, 32);
    pd += __shfl_xor(pd, 16); pd += __shfl_xor(pd, 32);
    if (q == 0 && arow < M) { svec[arow] = ps; dvec[arow] = pd; }

    // m store (fp32)
#pragma unroll
    for (int t = 0; t < 8; ++t) {
#pragma unroll
        for (int reg = 0; reg < 4; ++reg) {
            int r = r0 + q * 4 + reg;
            if (r < M) m[(size_t)r * D_OUT + t * 16 + c] = acc[t][reg];
        }
    }
}

// ---------------------------------------------------------------------------
// Dispatch 3: fill CSR, packed {dst, nv} int2, one 8B scattered store/edge
// ---------------------------------------------------------------------------
__global__ __launch_bounds__(256) void fill_kernel(
    const int* __restrict__ src, const int* __restrict__ dst,
    const float* __restrict__ nvals, int* __restrict__ cursor,
    int2* __restrict__ edges, int E) {
    int base = (blockIdx.x * 256 + (int)threadIdx.x) * 4;
    if (base + 4 <= E) {
        int4   s4 = *(const int4*)(src + base);
        int4   d4 = *(const int4*)(dst + base);
        float4 n4 = *(const float4*)(nvals + base);
        int p;
        p = atomicAdd(&cursor[s4.x], 1); edges[p] = make_int2(d4.x, __float_as_int(n4.x));
        p = atomicAdd(&cursor[s4.y], 1); edges[p] = make_int2(d4.y, __float_as_int(n4.y));
        p = atomicAdd(&cursor[s4.z], 1); edges[p] = make_int2(d4.z, __float_as_int(n4.z));
        p = atomicAdd(&cursor[s4.w], 1); edges[p] = make_int2(d4.w, __float_as_int(n4.w));
    } else {
        for (int i = base; i < E; ++i) {
            int p = atomicAdd(&cursor[src[i]], 1);
            edges[p] = make_int2(dst[i], __float_as_int(nvals[i]));
        }
    }
}

// ---------------------------------------------------------------------------
// Dispatch 4: one wave per row. Pass A: fp64 row_sum + cache {dst, nv*v} in
// LDS. Pass B: fp32 m gather (float2/lane), fp32 accumulate. No atomics.
// ---------------------------------------------------------------------------
__global__ __launch_bounds__(256) void row_kernel(
    const int* __restrict__ rowptr, const int2* __restrict__ edges,
    const double* __restrict__ svec, const double* __restrict__ dvec,
    const float* __restrict__ m, float* __restrict__ out, int M) {
    __shared__ int   s_dst[4][CAP];
    __shared__ float s_c[4][CAP];
    int w    = threadIdx.x >> 6;
    int lane = threadIdx.x & 63;
    int r    = blockIdx.x * 4 + w;
    if (r >= M) return;
    int beg = rowptr[r], end = rowptr[r + 1], len = end - beg;
    double sr  = svec[r];
    double sum = 0.0;
    for (int j = lane; j < len; j += 64) {
        int2 ed = edges[beg + j];
        double v = sr + dvec[ed.x];
        v = (v > 0.0) ? v : v * NEG_SLOPE;
        sum += v;
        if (j < CAP) {
            s_dst[w][j] = ed.x;
            s_c[w][j]   = (float)((double)__int_as_float(ed.y) * v);
        }
    }
#pragma unroll
    for (int off = 32; off > 0; off >>= 1) sum += __shfl_xor(sum, off);
    float invf = (float)(1.0 / sum);
    __builtin_amdgcn_wave_barrier();   // order LDS writes (pass A) before reads

    float2 acc = make_float2(0.f, 0.f);
    int lim = len < CAP ? len : CAP;
    int j = 0;
    for (; j + 8 <= lim; j += 8) {
        float2 mv[8]; float c8[8];
#pragma unroll
        for (int k = 0; k < 8; ++k) {
            int d = s_dst[w][j + k];
            c8[k] = s_c[w][j + k] * invf;
            mv[k] = ((const float2*)(m + (size_t)d * D_OUT))[lane];
        }
#pragma unroll
        for (int k = 0; k < 8; ++k) {
            acc.x = fmaf(c8[k], mv[k].x, acc.x);
            acc.y = fmaf(c8[k], mv[k].y, acc.y);
        }
    }
    for (; j < lim; ++j) {
        int d = s_dst[w][j];
        float cc = s_c[w][j] * invf;
        float2 mv = ((const float2*)(m + (size_t)d * D_OUT))[lane];
        acc.x = fmaf(cc, mv.x, acc.x);
        acc.y = fmaf(cc, mv.y, acc.y);
    }
    for (; j < len; ++j) {   // overflow (len > CAP): recompute inline
        int2 ed = edges[beg + j];
        double v = sr + dvec[ed.x];
        v = (v > 0.0) ? v : v * NEG_SLOPE;
        float cc = (float)((double)__int_as_float(ed.y) * v) * invf;
        float2 mv = ((const float2*)(m + (size_t)ed.x * D_OUT))[lane];
        acc.x = fmaf(cc, mv.x, acc.x);
        acc.y = fmaf(cc, mv.y, acc.y);
    }
    ((float2*)(out + (size_t)r * D_OUT))[lane] = acc;
}

// ---------------------------------------------------------------------------
extern "C" void kernel_launch(void* const* d_in, const int* in_sizes, int n_in,
                              void* d_out, int out_size, void* d_ws, size_t ws_size,
                              hipStream_t stream) {
    const float* x     = (const float*)d_in[0];
    const float* W     = (const float*)d_in[1];
    const float* a     = (const float*)d_in[2];
    const float* nvals = (const float*)d_in[3];
    const int*   nsrc  = (const int*)d_in[4];
    const int*   ndst  = (const int*)d_in[5];
    const int M = in_sizes[0] / D_IN;   // 50000
    const int E = in_sizes[4];          // 1600000
    float* out = (float*)d_out;

    char* ws = (char*)d_ws;
    size_t off = 0;
    float*  m    = (float*)(ws + off);           off += (size_t)M * D_OUT * sizeof(float); // 25.6 MB
    unsigned short* wth = (unsigned short*)(ws + off); off += (size_t)D_OUT * D_IN * 2;    // 64 KB
    unsigned short* wtl = (unsigned short*)(ws + off); off += (size_t)D_OUT * D_IN * 2;    // 64 KB
    double* wa   = (double*)(ws + off);          off += (size_t)2 * D_IN * sizeof(double); // 4 KB
    double* svec = (double*)(ws + off);          off += (size_t)M * sizeof(double);
    double* dvec = (double*)(ws + off);          off += (size_t)M * sizeof(double);
    int*    counts = (int*)(ws + off);  off += ((size_t)M * sizeof(int) + 15) & ~15ull;
    int*    rowptr = (int*)(ws + off);  off += ((size_t)(M + 1) * sizeof(int) + 15) & ~15ull;
    int*    cursor = (int*)(ws + off);  off += ((size_t)M * sizeof(int) + 15) & ~15ull;
    int2*   edges  = (int2*)(ws + off); off += (size_t)E * sizeof(int2);                   // 12.8 MB

    hipMemsetAsync(counts, 0, (size_t)M * sizeof(int), stream);

    const int countBlocks = (E + 1023) / 1024;   // 1563
    const int gemmBlocks  = (M + 63) / 64;       // 782

    prep_count<<<129 + countBlocks, 256, 0, stream>>>(W, a, wa, wth, wtl, nsrc, counts, E);
    gemm_sd_scan<<<1 + gemmBlocks, 256, 0, stream>>>(x, wth, wtl, wa, m, svec, dvec,
                                                     counts, rowptr, cursor, M);
    fill_kernel<<<countBlocks, 256, 0, stream>>>(nsrc, ndst, nvals, cursor, edges, E);
    row_kernel<<<(M + 3) / 4, 256, 0, stream>>>(rowptr, edges, svec, dvec, m, out, M);
}